// Round 1
// baseline (209.673 us; speedup 1.0000x reference)
//
#include <hip/hip_runtime.h>

// Problem constants (from reference): B=512, T=2048, C=32
#define BDIM 512
#define TDIM 2048
#define CDIM 32
#define BLOCK 256
#define CHUNKS (TDIM / BLOCK)   // 8 blocks per batch row
#define NBLK (BDIM * CHUNKS)    // 4096 blocks

// ws layout (floats): [0,32) colsum | [32,1056) E=exp(trans) | [2048, 2048+NBLK) partials

__global__ void crf_prep(const float* __restrict__ trans, float* __restrict__ ws) {
    int i = threadIdx.x;  // 1024 threads
    float* colsum = ws;
    float* E = ws + 32;
    E[i] = __expf(trans[i]);
    if (i < CDIM) {
        float s = 0.f;
        #pragma unroll
        for (int r = 0; r < CDIM; ++r) s += trans[r * CDIM + i];
        colsum[i] = s;
    }
}

__global__ __launch_bounds__(BLOCK) void crf_main(
        const float* __restrict__ P, const int* __restrict__ TT,
        const int* __restrict__ LEN, const float* __restrict__ ws,
        float* __restrict__ partials) {
    const float* colsum = ws;
    const float* E = ws + 32;

    const int blk = blockIdx.x;
    const int b = blk >> 3;       // CHUNKS = 8
    const int chunk = blk & 7;
    const int t = chunk * BLOCK + threadIdx.x;
    const int len = LEN[b];       // uniform per block
    const long rowbase = ((long)b * TDIM + t) * CDIM;

    const int tt = TT[b * TDIM + t];
    const int tt2 = (t < TDIM - 1) ? TT[b * TDIM + t + 1] : CDIM;  // sentinel kills g at t=T-1

    float h = 0.f, g = 0.f, z = 0.f;
    if (tt < CDIM) {
        h = P[rowbase + tt];              // gather; hits L1 when row also loaded
        if (tt2 < CDIM) g = colsum[tt];
    }

    const bool heavy = (t >= 1 && t <= len);
    if (heavy || t == 0) {
        const float4* row4 = reinterpret_cast<const float4*>(P + rowbase);
        float p[CDIM];
        #pragma unroll
        for (int q = 0; q < 8; ++q) {
            float4 v = row4[q];
            p[q * 4 + 0] = v.x; p[q * 4 + 1] = v.y;
            p[q * 4 + 2] = v.z; p[q * 4 + 3] = v.w;
        }
        if (t == 0) {
            float s = 0.f;
            #pragma unroll
            for (int y = 0; y < CDIM; ++y) s += p[y];
            z = s;
        } else {
            float ep[CDIM];
            #pragma unroll
            for (int y = 0; y < CDIM; ++y) ep[y] = __expf(p[y]);
            float R2 = 0.f;
            #pragma unroll
            for (int x = 0; x < CDIM; x += 4) {
                float a0 = 0.f, a1 = 0.f, a2 = 0.f, a3 = 0.f;
                #pragma unroll
                for (int y = 0; y < CDIM; ++y) {
                    a0 = fmaf(ep[y], E[(x + 0) * CDIM + y], a0);
                    a1 = fmaf(ep[y], E[(x + 1) * CDIM + y], a1);
                    a2 = fmaf(ep[y], E[(x + 2) * CDIM + y], a2);
                    a3 = fmaf(ep[y], E[(x + 3) * CDIM + y], a3);
                }
                R2 += __log2f(a0) + __log2f(a1) + __log2f(a2) + __log2f(a3);
            }
            z = R2 * 0.6931471805599453f;   // log(x) = log2(x)*ln2
        }
    }

    float v = 32.f * z - h - g;
    // wave reduce (64 lanes)
    #pragma unroll
    for (int off = 32; off; off >>= 1) v += __shfl_down(v, off);
    __shared__ float red[BLOCK / 64];
    if ((threadIdx.x & 63) == 0) red[threadIdx.x >> 6] = v;
    __syncthreads();
    if (threadIdx.x == 0)
        partials[blk] = red[0] + red[1] + red[2] + red[3];
}

__global__ void crf_finish(const float* __restrict__ partials, float* __restrict__ out) {
    double s = 0.0;
    for (int i = threadIdx.x; i < NBLK; i += 256) s += (double)partials[i];
    #pragma unroll
    for (int off = 32; off; off >>= 1) s += __shfl_down(s, off);
    __shared__ double red[4];
    if ((threadIdx.x & 63) == 0) red[threadIdx.x >> 6] = s;
    __syncthreads();
    if (threadIdx.x == 0) out[0] = (float)((red[0] + red[1] + red[2] + red[3]) / (double)BDIM);
}

extern "C" void kernel_launch(void* const* d_in, const int* in_sizes, int n_in,
                              void* d_out, int out_size, void* d_ws, size_t ws_size,
                              hipStream_t stream) {
    const float* P     = (const float*)d_in[0];   // target_predict (B,T,C) f32
    const float* trans = (const float*)d_in[1];   // (C,C) f32
    const int*   TT    = (const int*)d_in[2];     // target_true (B,T) int
    const int*   LEN   = (const int*)d_in[3];     // lens (B,) int
    float* out = (float*)d_out;
    float* ws  = (float*)d_ws;
    float* partials = ws + 2048;

    hipLaunchKernelGGL(crf_prep,   dim3(1),    dim3(1024), 0, stream, trans, ws);
    hipLaunchKernelGGL(crf_main,   dim3(NBLK), dim3(BLOCK), 0, stream, P, TT, LEN, ws, partials);
    hipLaunchKernelGGL(crf_finish, dim3(1),    dim3(256),  0, stream, partials, out);
}

// Round 2
// 209.452 us; speedup vs baseline: 1.0011x; 1.0011x over previous
//
#include <hip/hip_runtime.h>
#include <stdint.h>

// Problem constants (from reference): B=512, T=2048, C=32
#define BDIM 512
#define TDIM 2048
#define CDIM 32
#define BLOCK 256
#define CHUNKS (TDIM / BLOCK)   // 8 blocks per batch row
#define NBLK (BDIM * CHUNKS)    // 4096 blocks

// ws layout (floats):
//   [0,32)        colsum(trans) per column
//   [32,1056)     E = exp(trans) f32 (fallback path)
//   [1056,1568)   E packed half2: u32[x*16+j] = (E[x][2j], E[x][2j+1])
//   [2048,2048+NBLK) block partials

typedef _Float16 h2 __attribute__((ext_vector_type(2)));

#define HAVE_DOT2 __has_builtin(__builtin_amdgcn_fdot2)

__global__ void crf_prep(const float* __restrict__ trans, float* __restrict__ ws) {
    int i = threadIdx.x;  // 1024 threads
    float* colsum = ws;
    float* E = ws + 32;
    uint32_t* Eh = (uint32_t*)(ws + 1056);
    E[i] = __expf(trans[i]);
    if (i < 512) {
        h2 v;
        v.x = (_Float16)__expf(trans[2 * i]);
        v.y = (_Float16)__expf(trans[2 * i + 1]);
        Eh[i] = *(uint32_t*)&v;
    }
    if (i < CDIM) {
        float s = 0.f;
        #pragma unroll
        for (int r = 0; r < CDIM; ++r) s += trans[r * CDIM + i];
        colsum[i] = s;
    }
}

__global__ __launch_bounds__(BLOCK) void crf_main(
        const float* __restrict__ P, const int* __restrict__ TT,
        const int* __restrict__ LEN, const float* __restrict__ ws,
        float* __restrict__ partials) {
#if HAVE_DOT2
    __shared__ uint32_t sE[512];       // half2-packed E rows
#else
    __shared__ float sE[1024];         // f32 E
#endif
    __shared__ float sCol[CDIM];

    // stage E + colsum into LDS (uniform broadcast reads later)
#if HAVE_DOT2
    {
        const uint32_t* Eh = (const uint32_t*)(ws + 1056);
        for (int i = threadIdx.x; i < 512; i += BLOCK) sE[i] = Eh[i];
    }
#else
    for (int i = threadIdx.x; i < 1024; i += BLOCK) sE[i] = ws[32 + i];
#endif
    if (threadIdx.x < CDIM) sCol[threadIdx.x] = ws[threadIdx.x];
    __syncthreads();

    const int blk = blockIdx.x;
    const int b = blk >> 3;       // CHUNKS = 8
    const int chunk = blk & 7;
    const int t = chunk * BLOCK + threadIdx.x;
    const int len = LEN[b];       // uniform per block
    const long rowbase = ((long)b * TDIM + t) * CDIM;

    const int tt = TT[b * TDIM + t];
    const int tt2 = (t < TDIM - 1) ? TT[b * TDIM + t + 1] : CDIM;  // sentinel kills g at t=T-1

    float h = 0.f, g = 0.f, z = 0.f;
    if (tt < CDIM) {
        h = P[rowbase + tt];              // L1-hit for heavy rows
        if (tt2 < CDIM) g = sCol[tt];
    }

    const bool heavy = (t >= 1 && t <= len);
    if (heavy || t == 0) {
        const float4* row4 = reinterpret_cast<const float4*>(P + rowbase);
        float p[CDIM];
        #pragma unroll
        for (int q = 0; q < 8; ++q) {
            float4 v = row4[q];
            p[q * 4 + 0] = v.x; p[q * 4 + 1] = v.y;
            p[q * 4 + 2] = v.z; p[q * 4 + 3] = v.w;
        }
        if (t == 0) {
            float s = 0.f;
            #pragma unroll
            for (int y = 0; y < CDIM; ++y) s += p[y];
            z = s;
        } else {
#if HAVE_DOT2
            h2 eph[16];
            #pragma unroll
            for (int j = 0; j < 16; ++j) {
                h2 v;
                v.x = (_Float16)__expf(p[2 * j]);
                v.y = (_Float16)__expf(p[2 * j + 1]);
                eph[j] = v;
            }
            float R2 = 0.f;
            #pragma unroll
            for (int x = 0; x < CDIM; x += 4) {
                float a0 = 0.f, a1 = 0.f, a2 = 0.f, a3 = 0.f;
                #pragma unroll
                for (int j = 0; j < 16; ++j) {
                    h2 e0 = *reinterpret_cast<const h2*>(&sE[(x + 0) * 16 + j]);
                    h2 e1 = *reinterpret_cast<const h2*>(&sE[(x + 1) * 16 + j]);
                    h2 e2 = *reinterpret_cast<const h2*>(&sE[(x + 2) * 16 + j]);
                    h2 e3 = *reinterpret_cast<const h2*>(&sE[(x + 3) * 16 + j]);
                    a0 = __builtin_amdgcn_fdot2(eph[j], e0, a0, false);
                    a1 = __builtin_amdgcn_fdot2(eph[j], e1, a1, false);
                    a2 = __builtin_amdgcn_fdot2(eph[j], e2, a2, false);
                    a3 = __builtin_amdgcn_fdot2(eph[j], e3, a3, false);
                }
                R2 += __log2f(a0) + __log2f(a1) + __log2f(a2) + __log2f(a3);
            }
            z = R2 * 0.6931471805599453f;   // log(x) = log2(x)*ln2
#else
            float ep[CDIM];
            #pragma unroll
            for (int y = 0; y < CDIM; ++y) ep[y] = __expf(p[y]);
            float R2 = 0.f;
            #pragma unroll
            for (int x = 0; x < CDIM; x += 4) {
                float a0 = 0.f, a1 = 0.f, a2 = 0.f, a3 = 0.f;
                #pragma unroll
                for (int y = 0; y < CDIM; ++y) {
                    a0 = fmaf(ep[y], sE[(x + 0) * CDIM + y], a0);
                    a1 = fmaf(ep[y], sE[(x + 1) * CDIM + y], a1);
                    a2 = fmaf(ep[y], sE[(x + 2) * CDIM + y], a2);
                    a3 = fmaf(ep[y], sE[(x + 3) * CDIM + y], a3);
                }
                R2 += __log2f(a0) + __log2f(a1) + __log2f(a2) + __log2f(a3);
            }
            z = R2 * 0.6931471805599453f;
#endif
        }
    }

    float v = 32.f * z - h - g;
    // wave reduce (64 lanes)
    #pragma unroll
    for (int off = 32; off; off >>= 1) v += __shfl_down(v, off);
    __shared__ float red[BLOCK / 64];
    if ((threadIdx.x & 63) == 0) red[threadIdx.x >> 6] = v;
    __syncthreads();
    if (threadIdx.x == 0)
        partials[blk] = red[0] + red[1] + red[2] + red[3];
}

__global__ void crf_finish(const float* __restrict__ partials, float* __restrict__ out) {
    double s = 0.0;
    for (int i = threadIdx.x; i < NBLK; i += 256) s += (double)partials[i];
    #pragma unroll
    for (int off = 32; off; off >>= 1) s += __shfl_down(s, off);
    __shared__ double red[4];
    if ((threadIdx.x & 63) == 0) red[threadIdx.x >> 6] = s;
    __syncthreads();
    if (threadIdx.x == 0) out[0] = (float)((red[0] + red[1] + red[2] + red[3]) / (double)BDIM);
}

extern "C" void kernel_launch(void* const* d_in, const int* in_sizes, int n_in,
                              void* d_out, int out_size, void* d_ws, size_t ws_size,
                              hipStream_t stream) {
    const float* P     = (const float*)d_in[0];   // target_predict (B,T,C) f32
    const float* trans = (const float*)d_in[1];   // (C,C) f32
    const int*   TT    = (const int*)d_in[2];     // target_true (B,T) int
    const int*   LEN   = (const int*)d_in[3];     // lens (B,) int
    float* out = (float*)d_out;
    float* ws  = (float*)d_ws;
    float* partials = ws + 2048;

    hipLaunchKernelGGL(crf_prep,   dim3(1),    dim3(1024), 0, stream, trans, ws);
    hipLaunchKernelGGL(crf_main,   dim3(NBLK), dim3(BLOCK), 0, stream, P, TT, LEN, ws, partials);
    hipLaunchKernelGGL(crf_finish, dim3(1),    dim3(256),  0, stream, partials, out);
}

// Round 3
// 204.408 us; speedup vs baseline: 1.0258x; 1.0247x over previous
//
#include <hip/hip_runtime.h>
#include <stdint.h>

// Problem constants (from reference): B=512, T=2048, C=32
#define BDIM 512
#define TDIM 2048
#define CDIM 32
#define BLOCK 256
#define CHUNKS (TDIM / BLOCK)   // 8 blocks per batch row
#define NBLK (BDIM * CHUNKS)    // 4096 blocks

using bf16x8 = __attribute__((ext_vector_type(8))) short;
using f32x16 = __attribute__((ext_vector_type(16))) float;
using f32x4  = __attribute__((ext_vector_type(4))) float;

__device__ inline unsigned short f2bf(float f) {
    uint32_t u = __builtin_bit_cast(uint32_t, f);
    u += 0x7fff + ((u >> 16) & 1);          // round-to-nearest-even
    return (unsigned short)(u >> 16);
}

// ws layout (floats): [2048, 2048+NBLK) block partials

__global__ __launch_bounds__(BLOCK) void crf_main(
        const float* __restrict__ P, const int* __restrict__ TT,
        const int* __restrict__ LEN, const float* __restrict__ trans,
        float* __restrict__ partials) {
    __shared__ unsigned short sEb[CDIM * CDIM];     // bf16 E[x][y] = exp(trans[x][y])
    __shared__ float sCol[CDIM];                    // column sums of trans
    __shared__ unsigned short epBuf[4 * 4 * 64 * 8]; // [wave][kchunk][row][8] bf16

    const int tid  = threadIdx.x;
    const int lane = tid & 63;
    const int wid  = tid >> 6;

    // ---- per-block prep: E (bf16) + colsum from trans (4 KB, L2-resident) ----
    #pragma unroll
    for (int q = 0; q < 4; ++q) {
        int i = q * BLOCK + tid;                    // 1024 elements, coalesced
        sEb[i] = f2bf(__expf(trans[i]));
    }
    if (tid < CDIM) {
        float s = 0.f;
        #pragma unroll
        for (int r = 0; r < CDIM; ++r) s += trans[r * CDIM + tid];
        sCol[tid] = s;
    }
    __syncthreads();

    // ---- B fragments (held in regs for whole kernel): B[k][n] = E[n][k] ----
    // lane l: n = l&31, k = ks*16 + 8*(l>>5) + j  (j = 0..7, contiguous bf16)
    bf16x8 bB0, bB1;
    {
        const int n  = lane & 31;
        const int kh = (lane >> 5) * 8;
        bB0 = *reinterpret_cast<const bf16x8*>(&sEb[n * CDIM + 0  + kh]);
        bB1 = *reinterpret_cast<const bf16x8*>(&sEb[n * CDIM + 16 + kh]);
    }

    const int blk   = blockIdx.x;
    const int b     = blk >> 3;                     // CHUNKS = 8
    const int chunk = blk & 7;
    const int t     = chunk * BLOCK + tid;
    const int len   = LEN[b];                       // uniform per block
    const long rowbase = ((long)b * TDIM + t) * CDIM;

    const int tt  = TT[b * TDIM + t];
    const int tt2 = (t < TDIM - 1) ? TT[b * TDIM + t + 1] : CDIM;  // sentinel kills g at T-1

    float h = 0.f, g = 0.f;
    if (tt < CDIM) {
        h = P[rowbase + tt];                        // same line as the row load
        if (tt2 < CDIM) g = sCol[tt];
    }

    float zpart = 0.f;                              // lane's contribution to Σ 32*z
    const int tbase = chunk * BLOCK + wid * 64;     // wave's first row t

    if (tbase <= len) {                             // wave-uniform: any useful row in window
        const bool heavy = (t >= 1) && (t <= len);
        float p[CDIM];
        if (heavy || t == 0) {
            const f32x4* row4 = reinterpret_cast<const f32x4*>(P + rowbase);
            #pragma unroll
            for (int q = 0; q < 8; ++q) {
                f32x4 v = row4[q];
                p[4*q+0] = v[0]; p[4*q+1] = v[1]; p[4*q+2] = v[2]; p[4*q+3] = v[3];
            }
        } else {
            #pragma unroll
            for (int y = 0; y < CDIM; ++y) p[y] = 0.f;
        }
        if (t == 0) {                               // Z_col0 row: plain sum, no LSE
            float s = 0.f;
            #pragma unroll
            for (int y = 0; y < CDIM; ++y) s += p[y];
            zpart += 32.f * s;
        }

        // ep -> bf16, staged to per-wave LDS region, layout [kchunk][row][8]
        unsigned short* epW = epBuf + wid * (4 * 64 * 8);
        #pragma unroll
        for (int c = 0; c < 4; ++c) {
            union { bf16x8 v; unsigned short u[8]; } pk;
            #pragma unroll
            for (int j = 0; j < 8; ++j) {
                float e = heavy ? __expf(p[c * 8 + j]) : 0.f;  // masked rows -> zero row
                pk.u[j] = f2bf(e);
            }
            *reinterpret_cast<bf16x8*>(&epW[(c * 64 + lane) * 8]) = pk.v;  // lane-contiguous
        }

        // A fragments from LDS (intra-wave dep; compiler inserts lgkmcnt)
        // lane l, tile T: m = T*32 + (l&31); k = ks*16 + 8*(l>>5) + j -> kchunk = ks*2 + (l>>5)
        float zlog = 0.f;
        const int chi = lane >> 5;
        #pragma unroll
        for (int T = 0; T < 2; ++T) {
            const int m = T * 32 + (lane & 31);
            bf16x8 a0 = *reinterpret_cast<const bf16x8*>(&epW[((0 + chi) * 64 + m) * 8]);
            bf16x8 a1 = *reinterpret_cast<const bf16x8*>(&epW[((2 + chi) * 64 + m) * 8]);
            f32x16 acc = {};
            acc = __builtin_amdgcn_mfma_f32_32x32x16_bf16(a0, bB0, acc, 0, 0, 0);
            acc = __builtin_amdgcn_mfma_f32_32x32x16_bf16(a1, bB1, acc, 0, 0, 0);
            // D layout (verified): col = lane&31, row = (r&3) + 8*(r>>2) + 4*(lane>>5)
            #pragma unroll
            for (int r = 0; r < 16; ++r) {
                const int row  = (r & 3) + 8 * (r >> 2) + 4 * chi + T * 32;
                const int trow = tbase + row;
                const bool valid = (trow >= 1) && (trow <= len);
                zlog += valid ? __log2f(acc[r]) : 0.f;
            }
        }
        zpart += 32.f * 0.6931471805599453f * zlog;  // 32 * ln2 * Σ log2
    }

    float v = zpart - h - g;
    // wave reduce (64 lanes) + block reduce
    #pragma unroll
    for (int off = 32; off; off >>= 1) v += __shfl_down(v, off);
    __shared__ float red[BLOCK / 64];
    if (lane == 0) red[wid] = v;
    __syncthreads();
    if (tid == 0)
        partials[blk] = red[0] + red[1] + red[2] + red[3];
}

__global__ void crf_finish(const float* __restrict__ partials, float* __restrict__ out) {
    double s = 0.0;
    for (int i = threadIdx.x; i < NBLK; i += 256) s += (double)partials[i];
    #pragma unroll
    for (int off = 32; off; off >>= 1) s += __shfl_down(s, off);
    __shared__ double red[4];
    if ((threadIdx.x & 63) == 0) red[threadIdx.x >> 6] = s;
    __syncthreads();
    if (threadIdx.x == 0) out[0] = (float)((red[0] + red[1] + red[2] + red[3]) / (double)BDIM);
}

extern "C" void kernel_launch(void* const* d_in, const int* in_sizes, int n_in,
                              void* d_out, int out_size, void* d_ws, size_t ws_size,
                              hipStream_t stream) {
    const float* P     = (const float*)d_in[0];   // target_predict (B,T,C) f32
    const float* trans = (const float*)d_in[1];   // (C,C) f32
    const int*   TT    = (const int*)d_in[2];     // target_true (B,T) int
    const int*   LEN   = (const int*)d_in[3];     // lens (B,) int
    float* out = (float*)d_out;
    float* ws  = (float*)d_ws;
    float* partials = ws + 2048;

    hipLaunchKernelGGL(crf_main,   dim3(NBLK), dim3(BLOCK), 0, stream, P, TT, LEN, trans, partials);
    hipLaunchKernelGGL(crf_finish, dim3(1),    dim3(256),   0, stream, partials, out);
}

// Round 6
// 203.449 us; speedup vs baseline: 1.0306x; 1.0047x over previous
//
#include <hip/hip_runtime.h>
#include <stdint.h>

// Problem constants (from reference): B=512, T=2048, C=32
#define BDIM 512
#define TDIM 2048
#define CDIM 32
#define BLOCK 256
#define CHUNKS 8                // blocks per batch row
#define NBLK (BDIM * CHUNKS)    // 4096 blocks

using bf16x8 = __attribute__((ext_vector_type(8))) short;
using f32x16 = __attribute__((ext_vector_type(16))) float;
using f32x4  = __attribute__((ext_vector_type(4))) float;

__device__ inline unsigned short f2bf(float f) {
    uint32_t u = __builtin_bit_cast(uint32_t, f);
    u += 0x7fff + ((u >> 16) & 1);          // round-to-nearest-even
    return (unsigned short)(u >> 16);
}

// XOR-swizzled byte slot for a 64-row x 16B LDS tile (bijective, 16B-aligned)
__device__ inline int swz16(int row) {
    return (row << 4) ^ (((row >> 3) & 3) << 4);
}

// ws layout (floats): [2048, 2048+NBLK) block partials

__global__ __launch_bounds__(BLOCK) void crf_main(
        const float* __restrict__ P, const int* __restrict__ TT,
        const int* __restrict__ LEN, const float* __restrict__ trans,
        float* __restrict__ partials) {
    __shared__ unsigned short sEb[CDIM * CDIM];   // bf16 E[x][y] = exp(trans[x][y])
    __shared__ float sCol[CDIM];                  // column sums of trans
    __shared__ char epBuf[4 * 4 * 1024];          // [wave][kchunk][64 rows x 16B, swizzled]

    const int tid  = threadIdx.x;
    const int lane = tid & 63;
    const int wid  = tid >> 6;

    const int blk   = blockIdx.x;
    const int b     = blk >> 3;                   // CHUNKS = 8
    const int chunk = blk & 7;
    const int t     = chunk * BLOCK + tid;
    const int len   = LEN[b];                     // uniform per block
    const long rowbase = ((long)b * TDIM + t) * CDIM;

    const bool blockHeavy = (chunk * BLOCK) <= len;   // chunk 0 always (len >= 0)

    // ---- prep: colsum always; E (bf16) only if this block has heavy rows ----
    if (tid < CDIM) {
        float s = 0.f;
        #pragma unroll
        for (int r = 0; r < CDIM; ++r) s += trans[r * CDIM + tid];
        sCol[tid] = s;
    }
    if (blockHeavy) {
        #pragma unroll
        for (int q = 0; q < 4; ++q) {
            int i = q * BLOCK + tid;              // 1024 elements, coalesced
            sEb[i] = f2bf(__expf(trans[i]));
        }
    }
    __syncthreads();

    // ---- B fragments: B[k][n] = E[n][k];  lane: n=l&31, k=ks*16+8*(l>>5)+j ----
    bf16x8 bB0, bB1;
    if (blockHeavy) {
        const int n  = lane & 31;
        const int kh = (lane >> 5) * 8;
        bB0 = *reinterpret_cast<const bf16x8*>(&sEb[n * CDIM + 0  + kh]);
        bB1 = *reinterpret_cast<const bf16x8*>(&sEb[n * CDIM + 16 + kh]);
    }

    const int tt  = TT[b * TDIM + t];
    const int tt2 = (t < TDIM - 1) ? TT[b * TDIM + t + 1] : CDIM;  // sentinel kills g at T-1

    float h = 0.f, g = 0.f;
    if (tt < CDIM) {
        h = P[rowbase + tt];                      // L1-hit for heavy rows
        if (tt2 < CDIM) g = sCol[tt];
    }

    float zpart = 0.f;                            // lane's contribution to Σ 32*z
    const int tbase = chunk * BLOCK + wid * 64;   // wave's first row t

    if (tbase <= len) {                           // wave-uniform guard
        const bool heavy = (t >= 1) && (t <= len);
        float p[CDIM];
        if (heavy || t == 0) {
            const f32x4* row4 = reinterpret_cast<const f32x4*>(P + rowbase);
            #pragma unroll
            for (int q = 0; q < 8; ++q) {
                f32x4 v = row4[q];
                p[4*q+0] = v[0]; p[4*q+1] = v[1]; p[4*q+2] = v[2]; p[4*q+3] = v[3];
            }
        } else {
            #pragma unroll
            for (int y = 0; y < CDIM; ++y) p[y] = 0.f;
        }
        if (t == 0) {                             // Z_col0 row: plain sum, no LSE
            float s = 0.f;
            #pragma unroll
            for (int y = 0; y < CDIM; ++y) s += p[y];
            zpart += 32.f * s;
        }

        // ep -> bf16, staged to per-wave LDS, layout [kchunk][row][8], XOR-swizzled
        char* epW = epBuf + wid * 4096;
        #pragma unroll
        for (int c = 0; c < 4; ++c) {
            union { bf16x8 v; unsigned short u[8]; } pk;
            #pragma unroll
            for (int j = 0; j < 8; ++j) {
                float e = heavy ? __expf(p[c * 8 + j]) : 0.f;  // masked rows -> zero row
                pk.u[j] = f2bf(e);
            }
            *reinterpret_cast<bf16x8*>(epW + c * 1024 + swz16(lane)) = pk.v;
        }

        // A fragments from LDS; lane l, tile T: m = T*32+(l&31); kchunk = ks*2+(l>>5)
        float zlog = 0.f;
        const int chi = lane >> 5;
        #pragma unroll
        for (int T = 0; T < 2; ++T) {
            const int m = T * 32 + (lane & 31);
            bf16x8 a0 = *reinterpret_cast<const bf16x8*>(epW + (0 + chi) * 1024 + swz16(m));
            bf16x8 a1 = *reinterpret_cast<const bf16x8*>(epW + (2 + chi) * 1024 + swz16(m));
            f32x16 acc = {};
            acc = __builtin_amdgcn_mfma_f32_32x32x16_bf16(a0, bB0, acc, 0, 0, 0);
            acc = __builtin_amdgcn_mfma_f32_32x32x16_bf16(a1, bB1, acc, 0, 0, 0);
            // D layout (verified): col = lane&31, row = (r&3) + 8*(r>>2) + 4*(lane>>5)
            float av[16];
            #pragma unroll
            for (int r = 0; r < 16; ++r) {
                const int row  = (r & 3) + 8 * (r >> 2) + 4 * chi + T * 32;
                const int trow = tbase + row;
                const bool valid = (trow >= 1) && (trow <= len);
                av[r] = valid ? acc[r] : 1.0f;
            }
            #pragma unroll
            for (int r = 0; r < 16; r += 2)       // pairwise: halve log2 count
                zlog += __log2f(av[r] * av[r + 1]);
        }
        zpart += 32.f * 0.6931471805599453f * zlog;  // 32 * ln2 * Σ log2
    }

    float v = zpart - h - g;
    // wave reduce (64 lanes) + block reduce
    #pragma unroll
    for (int off = 32; off; off >>= 1) v += __shfl_down(v, off);
    __shared__ float red[BLOCK / 64];
    if (lane == 0) red[wid] = v;
    __syncthreads();
    if (tid == 0)
        partials[blk] = red[0] + red[1] + red[2] + red[3];
}

__global__ __launch_bounds__(1024) void crf_finish(
        const float* __restrict__ partials, float* __restrict__ out) {
    const int tid = threadIdx.x;
    double s = 0.0;
    for (int i = tid; i < NBLK; i += 1024) s += (double)partials[i];
    #pragma unroll
    for (int off = 32; off; off >>= 1) s += __shfl_down(s, off);
    __shared__ double red[16];
    if ((tid & 63) == 0) red[tid >> 6] = s;
    __syncthreads();
    if (tid == 0) {
        double r = 0.0;
        #pragma unroll
        for (int w = 0; w < 16; ++w) r += red[w];
        out[0] = (float)(r / (double)BDIM);
    }
}

extern "C" void kernel_launch(void* const* d_in, const int* in_sizes, int n_in,
                              void* d_out, int out_size, void* d_ws, size_t ws_size,
                              hipStream_t stream) {
    const float* P     = (const float*)d_in[0];   // target_predict (B,T,C) f32
    const float* trans = (const float*)d_in[1];   // (C,C) f32
    const int*   TT    = (const int*)d_in[2];     // target_true (B,T) int
    const int*   LEN   = (const int*)d_in[3];     // lens (B,) int
    float* out = (float*)d_out;
    float* ws  = (float*)d_ws;
    float* partials = ws + 2048;

    hipLaunchKernelGGL(crf_main,   dim3(NBLK), dim3(BLOCK), 0, stream, P, TT, LEN, trans, partials);
    hipLaunchKernelGGL(crf_finish, dim3(1),    dim3(1024),  0, stream, partials, out);
}